// Round 1
// baseline (350.457 us; speedup 1.0000x reference)
//
#include <hip/hip_runtime.h>
#include <math.h>

#define CEPS 1e-9f

typedef _Float16 half8 __attribute__((ext_vector_type(8)));
typedef _Float16 h2 __attribute__((ext_vector_type(2)));
typedef __fp16 fp16x2 __attribute__((ext_vector_type(2)));
typedef float floatx16 __attribute__((ext_vector_type(16)));
typedef float f32x4v __attribute__((ext_vector_type(4)));

// x  : [4,56,56,8,32] fp32    W: [4,4,128,32] fp32    bias: [128] fp32
// out: [4,112,112,128] fp32 act
//
// R13: OCCUPANCY. R12 was latency-bound at 4 waves/SIMD (occ 38%, VALU 48%,
// MFMA 7%, HBM 8%): LDS 33.3KB/block AND unified-file regs 60 VGPR + 64 AGPR
// = 124 both capped blocks/CU at 4. Fixes:
//  (a) xt/scx share one 16.9KB LDS buffer (xt dead after K-loop; one extra
//      barrier).
//  (b) K-loop split into two 2-n-tile passes; each pass's acc (32 AGPR) is
//      pkrtz-packed to f16 pairs (il-dim) -> 32 h2 VGPRs hold all votes.
//      f16->f32->f16 round trips are exact: va2 bits identical to R12.
//  (c) __launch_bounds__(256,6) pins total regs <= 80 -> 6 waves/SIMD.
//  (d) nq / logit fdot2 chains split 4-way (32cy -> ~10cy dep latency).

template<int CTRL>
__device__ __forceinline__ float dpp_add(float v) {
    return v + __int_as_float(__builtin_amdgcn_update_dpp(
        0, __float_as_int(v), CTRL, 0xF, 0xF, false));
}
template<int CTRL>
__device__ __forceinline__ h2 dpp_add_h2(h2 v) {
    int t = __builtin_amdgcn_update_dpp(
        0, __builtin_bit_cast(int, v), CTRL, 0xF, 0xF, false);
    return v + __builtin_bit_cast(h2, t);
}
// sum over the 8-lane i-group (lane bits 0..2), both f16 components in parallel
__device__ __forceinline__ h2 sum_i8_h2(h2 v) {
    v = dpp_add_h2<0xB1>(v);     // quad_perm xor1
    v = dpp_add_h2<0x4E>(v);     // quad_perm xor2
    v = dpp_add_h2<0x141>(v);    // row_half_mirror (cross-quad)
    return v;
}
__device__ __forceinline__ h2 pkrtz(float a, float b) {
    return __builtin_bit_cast(h2, __builtin_amdgcn_cvt_pkrtz(a, b));
}
__device__ __forceinline__ float fdot2(h2 a, h2 b, float c) {
    return __builtin_amdgcn_fdot2(__builtin_bit_cast(fp16x2, a),
                                  __builtin_bit_cast(fp16x2, b), c, false);
}
__device__ __forceinline__ h2 hsel(bool c, h2 a, h2 b) {
    int r = c ? __builtin_bit_cast(int, a) : __builtin_bit_cast(int, b);
    return __builtin_bit_cast(h2, r);
}

// B[k][n] fragment table: idx = ((parity*8 + s)*4 + t)*64 + l -> 8 f16
__global__ __launch_bounds__(256) void prep_w(const float* __restrict__ Wt,
                                              _Float16* __restrict__ wb) {
    int idx = blockIdx.x * 256 + threadIdx.x;    // [0, 8192)
    int parity = idx >> 11;
    int s = (idx >> 8) & 7;
    int t = (idx >> 6) & 3;
    int l = idx & 63;
    int rh = parity >> 1, rw = parity & 1;
    int n = t * 32 + (l & 31);
    int h = l >> 5;
    int ci0 = ((s & 1) << 4) + (h << 3);
    int kh = ((s >> 2) << 1) + 1 - rh;
    int kw = (((s >> 1) & 1) << 1) + 1 - rw;
    const float* src = Wt + (((kh * 4 + kw) * 128 + n) << 5) + ci0;
    float4 w0 = *(const float4*)src;
    float4 w1 = *(const float4*)(src + 4);
    half8 hv;
    hv[0] = (_Float16)w0.x; hv[1] = (_Float16)w0.y;
    hv[2] = (_Float16)w0.z; hv[3] = (_Float16)w0.w;
    hv[4] = (_Float16)w1.x; hv[5] = (_Float16)w1.y;
    hv[6] = (_Float16)w1.z; hv[7] = (_Float16)w1.w;
    *(half8*)(wb + ((long)idx << 3)) = hv;
}

__global__ __launch_bounds__(256, 6) void caps_mfma(
    const float* __restrict__ x,
    const _Float16* __restrict__ wb,
    const float* __restrict__ bias,
    float* __restrict__ out)
{
    // Shared buffer, two lifetimes:
    //  phase 1 (stage + K-loop): xt = [cell(5x5)][i(8)][ci padded 32->40] f16, 16000 B
    //  phase 2 (routing):        scx = [wave(4)][1056] f32 transpose scratch, 16896 B
    __shared__ __align__(16) unsigned char smem[4 * 1056 * 4];
    _Float16* xt = (_Float16*)smem;
    float (*scx)[1056] = (float (*)[1056])smem;

    const int tid = threadIdx.x;
    const int tile = blockIdx.x;            // 0..195 : 14x14 tiles of 4x4 pixels
    const int tu = tile / 14, tv = tile - tu * 14;
    const int u0 = tu * 4, v0 = tv * 4;
    const int rh = blockIdx.y >> 1;         // p & 1
    const int rw = blockIdx.y & 1;          // q & 1
    const int bp = blockIdx.z;              // b'
    const _Float16* wsrc = wb + ((long)blockIdx.y << 14);   // parity slice, 16 KB

    // ---- stage x: fp32 -> f16 tile [ri(5)][rj(5)][i(8)][ci], zero-filled OOB ----
    #pragma unroll
    for (int it = 0; it < 4; ++it) {
        int idx = tid + (it << 8);
        if (idx < 800) {
            int cell = idx >> 5;            // 0..24
            int r = idx & 31;
            int i = r >> 2;
            int ci0 = (r & 3) << 3;
            int ri = cell / 5, rj = cell - ri * 5;
            int gi = u0 + rh - 1 + ri;
            int gj = v0 + rw - 1 + rj;
            float tmp[8] = {0.f, 0.f, 0.f, 0.f, 0.f, 0.f, 0.f, 0.f};
            if ((unsigned)gi < 56u && (unsigned)gj < 56u) {
                const float* src = x + (((i & 3) * 56 + gi) * 56 + gj) * 256
                                     + ((bp * 2 + (i >> 2)) << 5) + ci0;
                float4 a0 = *(const float4*)src;
                float4 a1 = *(const float4*)(src + 4);
                tmp[0] = a0.x; tmp[1] = a0.y; tmp[2] = a0.z; tmp[3] = a0.w;
                tmp[4] = a1.x; tmp[5] = a1.y; tmp[6] = a1.z; tmp[7] = a1.w;
            }
            half8 hv;
            #pragma unroll
            for (int j = 0; j < 8; ++j) hv[j] = (_Float16)tmp[j];
            *(half8*)(xt + (cell * 8 + i) * 40 + ci0) = hv;
        }
    }
    __syncthreads();

    const int l = tid & 63;
    const int w = tid >> 6;                 // wave = u-row within tile
    const int col = l & 31, h = l >> 5;
    const int invA = (l & 31) * 40 + (h << 3);

    // ---- MFMA K-loop, TWO passes of 2 n-tiles: acc is 32 AGPR (not 64). ----
    // After each pass, pack f32 acc -> f16 pairs along j (= pixl*4+il):
    // pf[t][m] = (votes[j=2m], votes[j=2m+1]) at ca = 32t+col.
    h2 pf[4][8];
    #pragma unroll
    for (int half = 0; half < 2; ++half) {
        floatx16 acc0, acc1;
        #pragma unroll
        for (int j = 0; j < 16; ++j) { acc0[j] = 0.f; acc1[j] = 0.f; }
        const int tb = half << 1;
        #pragma unroll
        for (int s = 0; s < 8; ++s) {
            const int tkh = s >> 2;
            const int tkw = (s >> 1) & 1;
            const int row = w + 1 - tkh;
            const int aoff = (row * 5 + 1 - tkw) * 320 + ((s & 1) << 4) + invA;
            half8 af = *(const half8*)(xt + aoff);
            half8 bf0 = *(const half8*)(wsrc + (((s * 4 + tb) * 64 + l) << 3));
            half8 bf1 = *(const half8*)(wsrc + (((s * 4 + tb + 1) * 64 + l) << 3));
            acc0 = __builtin_amdgcn_mfma_f32_32x32x16_f16(af, bf0, acc0, 0, 0, 0);
            acc1 = __builtin_amdgcn_mfma_f32_32x32x16_f16(af, bf1, acc1, 0, 0, 0);
        }
        #pragma unroll
        for (int m = 0; m < 8; ++m) {
            pf[tb][m]     = pkrtz(acc0[2 * m], acc0[2 * m + 1]);
            pf[tb + 1][m] = pkrtz(acc1[2 * m], acc1[2 * m + 1]);
        }
    }

    // xt is dead; scx aliases it. All waves must pass here before writing.
    __syncthreads();

    // ---- routing: lane = (c = l>>3, i = l&7); a(16) in-register as h2[8] ----
    float* scb = &scx[w][0];                // wave-local after the barrier
    const int cI = l >> 3;
    const int iI = l & 7;

    // bias as packed f16 pairs, loaded once (8 distinct addrs/wave -> L1)
    h2 bq2[8];
    {
        const float* bpt = bias + (cI << 4);
        float4 b0 = *(const float4*)bpt;
        float4 b1 = *(const float4*)(bpt + 4);
        float4 b2 = *(const float4*)(bpt + 8);
        float4 b3 = *(const float4*)(bpt + 12);
        bq2[0] = pkrtz(b0.x, b0.y); bq2[1] = pkrtz(b0.z, b0.w);
        bq2[2] = pkrtz(b1.x, b1.y); bq2[3] = pkrtz(b1.z, b1.w);
        bq2[4] = pkrtz(b2.x, b2.y); bq2[5] = pkrtz(b2.z, b2.w);
        bq2[6] = pkrtz(b3.x, b3.y); bq2[7] = pkrtz(b3.z, b3.w);
    }
    const h2 c0125 = pkrtz(0.125f, 0.125f);

    #pragma unroll
    for (int pixl = 0; pixl < 4; ++pixl) {
        // transpose: packed f16 votes -> [i][ca] f32 (row stride 132); i = 4h + il
        // (f16->f32 is exact; the later pkrtz re-pack gives bit-identical va2.)
        #pragma unroll
        for (int t = 0; t < 4; ++t)
            #pragma unroll
            for (int il = 0; il < 4; ++il) {
                h2 pp = pf[t][(pixl << 1) + (il >> 1)];
                float v = (il & 1) ? (float)pp.y : (float)pp.x;
                scb[((h << 2) + il) * 132 + t * 32 + col] = v;
            }

        // read my (c,i) row: 4x ds_read_b128, convert to 8 packed f16 pairs
        const float* rb = scb + iI * 132 + (cI << 4);
        f32x4v vq0 = *(const f32x4v*)(rb);
        f32x4v vq1 = *(const f32x4v*)(rb + 4);
        f32x4v vq2 = *(const f32x4v*)(rb + 8);
        f32x4v vq3 = *(const f32x4v*)(rb + 12);
        h2 va2[8];
        va2[0] = pkrtz(vq0.x, vq0.y); va2[1] = pkrtz(vq0.z, vq0.w);
        va2[2] = pkrtz(vq1.x, vq1.y); va2[3] = pkrtz(vq1.z, vq1.w);
        va2[4] = pkrtz(vq2.x, vq2.y); va2[5] = pkrtz(vq2.z, vq2.w);
        va2[6] = pkrtz(vq3.x, vq3.y); va2[7] = pkrtz(vq3.z, vq3.w);

        h2 pre2[8];
        float lg;

        // ---- round 0: route = 1/8 ----
        #pragma unroll
        for (int j = 0; j < 8; ++j) {
            h2 s2 = sum_i8_h2(va2[j]);
            pre2[j] = s2 * c0125 + bq2[j];           // v_pk_fma_f16
        }
        {
            float n0 = fdot2(pre2[0], pre2[0], 0.f);
            float n1 = fdot2(pre2[1], pre2[1], 0.f);
            float n2 = fdot2(pre2[2], pre2[2], 0.f);
            float n3 = fdot2(pre2[3], pre2[3], 0.f);
            n0 = fdot2(pre2[4], pre2[4], n0);
            n1 = fdot2(pre2[5], pre2[5], n1);
            n2 = fdot2(pre2[6], pre2[6], n2);
            n3 = fdot2(pre2[7], pre2[7], n3);
            float nq = (n0 + n1) + (n2 + n3);
            float sc = nq * __builtin_amdgcn_rcpf(1.f + nq)
                          * __builtin_amdgcn_rsqf(nq + CEPS);
            h2 sc2 = pkrtz(sc, sc);
            #pragma unroll
            for (int j = 0; j < 8; ++j) pre2[j] *= sc2;   // pre2 = act
            float d0 = fdot2(va2[0], pre2[0], 0.f);
            float d1 = fdot2(va2[1], pre2[1], 0.f);
            float d2 = fdot2(va2[2], pre2[2], 0.f);
            float d3 = fdot2(va2[3], pre2[3], 0.f);
            d0 = fdot2(va2[4], pre2[4], d0);
            d1 = fdot2(va2[5], pre2[5], d1);
            d2 = fdot2(va2[6], pre2[6], d2);
            d3 = fdot2(va2[7], pre2[7], d3);
            lg = (d0 + d1) + (d2 + d3);               // per-(i,c), fp32
        }

        // ---- rounds 1,2 ----
        #pragma unroll
        for (int r = 1; r < 3; ++r) {
            // softmax over c (lane bits 3..5); logits bounded, no max-sub; fp32
            float e = __expf(lg);
            float ss = dpp_add<0x128>(e);             // ror8 == xor8 (in-row)
            ss += __int_as_float(__builtin_amdgcn_ds_swizzle(
                      __float_as_int(ss), 0x401F));   // xor16
            ss += __shfl_xor(ss, 32);
            float route = e * __builtin_amdgcn_rcpf(ss);
            h2 rt2 = pkrtz(route, route);
            #pragma unroll
            for (int j = 0; j < 8; ++j) {
                h2 p = sum_i8_h2(rt2 * va2[j]);       // pk_mul + packed i-sum
                pre2[j] = p + bq2[j];                 // v_pk_add_f16
            }
            float n0 = fdot2(pre2[0], pre2[0], 0.f);
            float n1 = fdot2(pre2[1], pre2[1], 0.f);
            float n2 = fdot2(pre2[2], pre2[2], 0.f);
            float n3 = fdot2(pre2[3], pre2[3], 0.f);
            n0 = fdot2(pre2[4], pre2[4], n0);
            n1 = fdot2(pre2[5], pre2[5], n1);
            n2 = fdot2(pre2[6], pre2[6], n2);
            n3 = fdot2(pre2[7], pre2[7], n3);
            float nq = (n0 + n1) + (n2 + n3);
            float sc = nq * __builtin_amdgcn_rcpf(1.f + nq)
                          * __builtin_amdgcn_rsqf(nq + CEPS);
            h2 sc2 = pkrtz(sc, sc);
            #pragma unroll
            for (int j = 0; j < 8; ++j) pre2[j] *= sc2;   // act
            if (r < 2) {
                float d0 = fdot2(va2[0], pre2[0], lg);
                float d1 = fdot2(va2[1], pre2[1], 0.f);
                float d2 = fdot2(va2[2], pre2[2], 0.f);
                float d3 = fdot2(va2[3], pre2[3], 0.f);
                d0 = fdot2(va2[4], pre2[4], d0);
                d1 = fdot2(va2[5], pre2[5], d1);
                d2 = fdot2(va2[6], pre2[6], d2);
                d3 = fdot2(va2[7], pre2[7], d3);
                lg = (d0 + d1) + (d2 + d3);
            }
        }

        // ---- store: lanes i<4 each write one float4 quad -> fully coalesced ----
        if (iI < 4) {
            // quad q=iI covers pairs j0=2(iI&1)+4((iI>>1)&1), j0+1
            h2 h0 = hsel((iI & 2) != 0, pre2[4], pre2[0]);
            h2 h1 = hsel((iI & 2) != 0, pre2[5], pre2[1]);
            h2 h2_ = hsel((iI & 2) != 0, pre2[6], pre2[2]);
            h2 h3 = hsel((iI & 2) != 0, pre2[7], pre2[3]);
            h2 p0 = hsel((iI & 1) != 0, h2_, h0);
            h2 p1 = hsel((iI & 1) != 0, h3, h1);
            float4 o4 = make_float4((float)p0.x, (float)p0.y,
                                    (float)p1.x, (float)p1.y);
            const int p = ((u0 + w) << 1) + rh;
            const int q = ((v0 + pixl) << 1) + rw;
            *(float4*)(out + (((bp * 112 + p) * 112 + q) << 7) + cI * 16 + iI * 4) = o4;
        }
    }
}

extern "C" void kernel_launch(void* const* d_in, const int* in_sizes, int n_in,
                              void* d_out, int out_size, void* d_ws, size_t ws_size,
                              hipStream_t stream) {
    const float* x  = (const float*)d_in[0];
    const float* Wt = (const float*)d_in[1];
    const float* b  = (const float*)d_in[2];
    float* out = (float*)d_out;
    _Float16* wb = (_Float16*)d_ws;          // 4 parities x 16384 f16 = 64 KB

    prep_w<<<32, 256, 0, stream>>>(Wt, wb);
    dim3 grid(196, 4, 4);    // 14x14 4x4-pixel tiles, 4 parity classes, 4 b'
    caps_mfma<<<grid, 256, 0, stream>>>(x, wb, b, out);
}

// Round 2
// 150.745 us; speedup vs baseline: 2.3248x; 2.3248x over previous
//
#include <hip/hip_runtime.h>
#include <math.h>

#define CEPS 1e-9f

typedef _Float16 half8 __attribute__((ext_vector_type(8)));
typedef _Float16 h2 __attribute__((ext_vector_type(2)));
typedef __fp16 fp16x2 __attribute__((ext_vector_type(2)));
typedef float floatx16 __attribute__((ext_vector_type(16)));
typedef float f32x4v __attribute__((ext_vector_type(4)));

// x  : [4,56,56,8,32] fp32    W: [4,4,128,32] fp32    bias: [128] fp32
// out: [4,112,112,128] fp32 act
//
// R14: R13 retry with spill fix. R13's (256,6) cap (85 unified regs) spilled
// ~1.5KB/thread (WRITE 789MB vs 25MB out) because full unroll CSE'd the 8
// identical af LDS loads across the two K-pass halves -> +32 live VGPRs.
// Fix: launder the A-frag LDS offset through empty asm per (half,s) so the
// loads can't be unified, + sched_barrier(0) between halves so half-2 loads
// aren't pipelined into half-1. Peak live est ~68 -> fits 85.
// Everything else from R13 kept:
//  (a) xt/scx share one 16.9KB LDS buffer (xt dead after K-loop).
//  (b) K-loop in two 2-n-tile passes, acc=32 AGPR; votes pkrtz-packed to
//      32 h2 VGPRs (f16 round-trip exact -> va2 bits identical to R12).
//  (c) __launch_bounds__(256,6) -> 6 waves/SIMD target (R12 was 4, occ 38%,
//      VALU 48%, latency-bound).
//  (d) nq / logit fdot2 chains split 4-way.

template<int CTRL>
__device__ __forceinline__ float dpp_add(float v) {
    return v + __int_as_float(__builtin_amdgcn_update_dpp(
        0, __float_as_int(v), CTRL, 0xF, 0xF, false));
}
template<int CTRL>
__device__ __forceinline__ h2 dpp_add_h2(h2 v) {
    int t = __builtin_amdgcn_update_dpp(
        0, __builtin_bit_cast(int, v), CTRL, 0xF, 0xF, false);
    return v + __builtin_bit_cast(h2, t);
}
// sum over the 8-lane i-group (lane bits 0..2), both f16 components in parallel
__device__ __forceinline__ h2 sum_i8_h2(h2 v) {
    v = dpp_add_h2<0xB1>(v);     // quad_perm xor1
    v = dpp_add_h2<0x4E>(v);     // quad_perm xor2
    v = dpp_add_h2<0x141>(v);    // row_half_mirror (cross-quad)
    return v;
}
__device__ __forceinline__ h2 pkrtz(float a, float b) {
    return __builtin_bit_cast(h2, __builtin_amdgcn_cvt_pkrtz(a, b));
}
__device__ __forceinline__ float fdot2(h2 a, h2 b, float c) {
    return __builtin_amdgcn_fdot2(__builtin_bit_cast(fp16x2, a),
                                  __builtin_bit_cast(fp16x2, b), c, false);
}
__device__ __forceinline__ h2 hsel(bool c, h2 a, h2 b) {
    int r = c ? __builtin_bit_cast(int, a) : __builtin_bit_cast(int, b);
    return __builtin_bit_cast(h2, r);
}

// B[k][n] fragment table: idx = ((parity*8 + s)*4 + t)*64 + l -> 8 f16
__global__ __launch_bounds__(256) void prep_w(const float* __restrict__ Wt,
                                              _Float16* __restrict__ wb) {
    int idx = blockIdx.x * 256 + threadIdx.x;    // [0, 8192)
    int parity = idx >> 11;
    int s = (idx >> 8) & 7;
    int t = (idx >> 6) & 3;
    int l = idx & 63;
    int rh = parity >> 1, rw = parity & 1;
    int n = t * 32 + (l & 31);
    int h = l >> 5;
    int ci0 = ((s & 1) << 4) + (h << 3);
    int kh = ((s >> 2) << 1) + 1 - rh;
    int kw = (((s >> 1) & 1) << 1) + 1 - rw;
    const float* src = Wt + (((kh * 4 + kw) * 128 + n) << 5) + ci0;
    float4 w0 = *(const float4*)src;
    float4 w1 = *(const float4*)(src + 4);
    half8 hv;
    hv[0] = (_Float16)w0.x; hv[1] = (_Float16)w0.y;
    hv[2] = (_Float16)w0.z; hv[3] = (_Float16)w0.w;
    hv[4] = (_Float16)w1.x; hv[5] = (_Float16)w1.y;
    hv[6] = (_Float16)w1.z; hv[7] = (_Float16)w1.w;
    *(half8*)(wb + ((long)idx << 3)) = hv;
}

__global__ __launch_bounds__(256, 6) void caps_mfma(
    const float* __restrict__ x,
    const _Float16* __restrict__ wb,
    const float* __restrict__ bias,
    float* __restrict__ out)
{
    // Shared buffer, two lifetimes:
    //  phase 1 (stage + K-loop): xt = [cell(5x5)][i(8)][ci padded 32->40] f16, 16000 B
    //  phase 2 (routing):        scx = [wave(4)][1056] f32 transpose scratch, 16896 B
    __shared__ __align__(16) unsigned char smem[4 * 1056 * 4];
    _Float16* xt = (_Float16*)smem;
    float (*scx)[1056] = (float (*)[1056])smem;

    const int tid = threadIdx.x;
    const int tile = blockIdx.x;            // 0..195 : 14x14 tiles of 4x4 pixels
    const int tu = tile / 14, tv = tile - tu * 14;
    const int u0 = tu * 4, v0 = tv * 4;
    const int rh = blockIdx.y >> 1;         // p & 1
    const int rw = blockIdx.y & 1;          // q & 1
    const int bp = blockIdx.z;              // b'
    const _Float16* wsrc = wb + ((long)blockIdx.y << 14);   // parity slice, 16 KB

    // ---- stage x: fp32 -> f16 tile [ri(5)][rj(5)][i(8)][ci], zero-filled OOB ----
    #pragma unroll
    for (int it = 0; it < 4; ++it) {
        int idx = tid + (it << 8);
        if (idx < 800) {
            int cell = idx >> 5;            // 0..24
            int r = idx & 31;
            int i = r >> 2;
            int ci0 = (r & 3) << 3;
            int ri = cell / 5, rj = cell - ri * 5;
            int gi = u0 + rh - 1 + ri;
            int gj = v0 + rw - 1 + rj;
            float tmp[8] = {0.f, 0.f, 0.f, 0.f, 0.f, 0.f, 0.f, 0.f};
            if ((unsigned)gi < 56u && (unsigned)gj < 56u) {
                const float* src = x + (((i & 3) * 56 + gi) * 56 + gj) * 256
                                     + ((bp * 2 + (i >> 2)) << 5) + ci0;
                float4 a0 = *(const float4*)src;
                float4 a1 = *(const float4*)(src + 4);
                tmp[0] = a0.x; tmp[1] = a0.y; tmp[2] = a0.z; tmp[3] = a0.w;
                tmp[4] = a1.x; tmp[5] = a1.y; tmp[6] = a1.z; tmp[7] = a1.w;
            }
            half8 hv;
            #pragma unroll
            for (int j = 0; j < 8; ++j) hv[j] = (_Float16)tmp[j];
            *(half8*)(xt + (cell * 8 + i) * 40 + ci0) = hv;
        }
    }
    __syncthreads();

    const int l = tid & 63;
    const int w = tid >> 6;                 // wave = u-row within tile
    const int col = l & 31, h = l >> 5;
    const int invA = (l & 31) * 40 + (h << 3);

    // ---- MFMA K-loop, TWO passes of 2 n-tiles: acc is 32 AGPR (not 64). ----
    // After each pass, pack f32 acc -> f16 pairs along j (= pixl*4+il):
    // pf[t][m] = (votes[j=2m], votes[j=2m+1]) at ca = 32t+col.
    h2 pf[4][8];
    #pragma unroll
    for (int half = 0; half < 2; ++half) {
        floatx16 acc0, acc1;
        #pragma unroll
        for (int j = 0; j < 16; ++j) { acc0[j] = 0.f; acc1[j] = 0.f; }
        const int tb = half << 1;
        #pragma unroll
        for (int s = 0; s < 8; ++s) {
            const int tkh = s >> 2;
            const int tkw = (s >> 1) & 1;
            const int row = w + 1 - tkh;
            int aoff = (row * 5 + 1 - tkw) * 320 + ((s & 1) << 4) + invA;
            // SPILL FIX: make the A-frag address opaque so the compiler
            // cannot CSE/hoist the 8 identical xt loads across the two
            // halves (R13: that hoisting (+32 VGPR) spilled at the 85-reg
            // cap -> 1.2GB scratch traffic).
            asm("" : "+v"(aoff));
            half8 af = *(const half8*)(xt + aoff);
            half8 bf0 = *(const half8*)(wsrc + (((s * 4 + tb) * 64 + l) << 3));
            half8 bf1 = *(const half8*)(wsrc + (((s * 4 + tb + 1) * 64 + l) << 3));
            acc0 = __builtin_amdgcn_mfma_f32_32x32x16_f16(af, bf0, acc0, 0, 0, 0);
            acc1 = __builtin_amdgcn_mfma_f32_32x32x16_f16(af, bf1, acc1, 0, 0, 0);
        }
        #pragma unroll
        for (int m = 0; m < 8; ++m) {
            pf[tb][m]     = pkrtz(acc0[2 * m], acc0[2 * m + 1]);
            pf[tb + 1][m] = pkrtz(acc1[2 * m], acc1[2 * m + 1]);
        }
        // keep half-2's loads from being software-pipelined into half-1
        // (would extend acc/af liveness across the packing)
        __builtin_amdgcn_sched_barrier(0);
    }

    // xt is dead; scx aliases it. All waves must pass here before writing.
    __syncthreads();

    // ---- routing: lane = (c = l>>3, i = l&7); a(16) in-register as h2[8] ----
    float* scb = &scx[w][0];                // wave-local after the barrier
    const int cI = l >> 3;
    const int iI = l & 7;

    // bias as packed f16 pairs, loaded once (8 distinct addrs/wave -> L1)
    h2 bq2[8];
    {
        const float* bpt = bias + (cI << 4);
        float4 b0 = *(const float4*)bpt;
        float4 b1 = *(const float4*)(bpt + 4);
        float4 b2 = *(const float4*)(bpt + 8);
        float4 b3 = *(const float4*)(bpt + 12);
        bq2[0] = pkrtz(b0.x, b0.y); bq2[1] = pkrtz(b0.z, b0.w);
        bq2[2] = pkrtz(b1.x, b1.y); bq2[3] = pkrtz(b1.z, b1.w);
        bq2[4] = pkrtz(b2.x, b2.y); bq2[5] = pkrtz(b2.z, b2.w);
        bq2[6] = pkrtz(b3.x, b3.y); bq2[7] = pkrtz(b3.z, b3.w);
    }
    const h2 c0125 = pkrtz(0.125f, 0.125f);

    #pragma unroll
    for (int pixl = 0; pixl < 4; ++pixl) {
        // transpose: packed f16 votes -> [i][ca] f32 (row stride 132); i = 4h + il
        // (f16->f32 is exact; the later pkrtz re-pack gives bit-identical va2.)
        #pragma unroll
        for (int t = 0; t < 4; ++t)
            #pragma unroll
            for (int il = 0; il < 4; ++il) {
                h2 pp = pf[t][(pixl << 1) + (il >> 1)];
                float v = (il & 1) ? (float)pp.y : (float)pp.x;
                scb[((h << 2) + il) * 132 + t * 32 + col] = v;
            }

        // read my (c,i) row: 4x ds_read_b128, convert to 8 packed f16 pairs
        const float* rb = scb + iI * 132 + (cI << 4);
        f32x4v vq0 = *(const f32x4v*)(rb);
        f32x4v vq1 = *(const f32x4v*)(rb + 4);
        f32x4v vq2 = *(const f32x4v*)(rb + 8);
        f32x4v vq3 = *(const f32x4v*)(rb + 12);
        h2 va2[8];
        va2[0] = pkrtz(vq0.x, vq0.y); va2[1] = pkrtz(vq0.z, vq0.w);
        va2[2] = pkrtz(vq1.x, vq1.y); va2[3] = pkrtz(vq1.z, vq1.w);
        va2[4] = pkrtz(vq2.x, vq2.y); va2[5] = pkrtz(vq2.z, vq2.w);
        va2[6] = pkrtz(vq3.x, vq3.y); va2[7] = pkrtz(vq3.z, vq3.w);

        h2 pre2[8];
        float lg;

        // ---- round 0: route = 1/8 ----
        #pragma unroll
        for (int j = 0; j < 8; ++j) {
            h2 s2 = sum_i8_h2(va2[j]);
            pre2[j] = s2 * c0125 + bq2[j];           // v_pk_fma_f16
        }
        {
            float n0 = fdot2(pre2[0], pre2[0], 0.f);
            float n1 = fdot2(pre2[1], pre2[1], 0.f);
            float n2 = fdot2(pre2[2], pre2[2], 0.f);
            float n3 = fdot2(pre2[3], pre2[3], 0.f);
            n0 = fdot2(pre2[4], pre2[4], n0);
            n1 = fdot2(pre2[5], pre2[5], n1);
            n2 = fdot2(pre2[6], pre2[6], n2);
            n3 = fdot2(pre2[7], pre2[7], n3);
            float nq = (n0 + n1) + (n2 + n3);
            float sc = nq * __builtin_amdgcn_rcpf(1.f + nq)
                          * __builtin_amdgcn_rsqf(nq + CEPS);
            h2 sc2 = pkrtz(sc, sc);
            #pragma unroll
            for (int j = 0; j < 8; ++j) pre2[j] *= sc2;   // pre2 = act
            float d0 = fdot2(va2[0], pre2[0], 0.f);
            float d1 = fdot2(va2[1], pre2[1], 0.f);
            float d2 = fdot2(va2[2], pre2[2], 0.f);
            float d3 = fdot2(va2[3], pre2[3], 0.f);
            d0 = fdot2(va2[4], pre2[4], d0);
            d1 = fdot2(va2[5], pre2[5], d1);
            d2 = fdot2(va2[6], pre2[6], d2);
            d3 = fdot2(va2[7], pre2[7], d3);
            lg = (d0 + d1) + (d2 + d3);               // per-(i,c), fp32
        }

        // ---- rounds 1,2 ----
        #pragma unroll
        for (int r = 1; r < 3; ++r) {
            // softmax over c (lane bits 3..5); logits bounded, no max-sub; fp32
            float e = __expf(lg);
            float ss = dpp_add<0x128>(e);             // ror8 == xor8 (in-row)
            ss += __int_as_float(__builtin_amdgcn_ds_swizzle(
                      __float_as_int(ss), 0x401F));   // xor16
            ss += __shfl_xor(ss, 32);
            float route = e * __builtin_amdgcn_rcpf(ss);
            h2 rt2 = pkrtz(route, route);
            #pragma unroll
            for (int j = 0; j < 8; ++j) {
                h2 p = sum_i8_h2(rt2 * va2[j]);       // pk_mul + packed i-sum
                pre2[j] = p + bq2[j];                 // v_pk_add_f16
            }
            float n0 = fdot2(pre2[0], pre2[0], 0.f);
            float n1 = fdot2(pre2[1], pre2[1], 0.f);
            float n2 = fdot2(pre2[2], pre2[2], 0.f);
            float n3 = fdot2(pre2[3], pre2[3], 0.f);
            n0 = fdot2(pre2[4], pre2[4], n0);
            n1 = fdot2(pre2[5], pre2[5], n1);
            n2 = fdot2(pre2[6], pre2[6], n2);
            n3 = fdot2(pre2[7], pre2[7], n3);
            float nq = (n0 + n1) + (n2 + n3);
            float sc = nq * __builtin_amdgcn_rcpf(1.f + nq)
                          * __builtin_amdgcn_rsqf(nq + CEPS);
            h2 sc2 = pkrtz(sc, sc);
            #pragma unroll
            for (int j = 0; j < 8; ++j) pre2[j] *= sc2;   // act
            if (r < 2) {
                float d0 = fdot2(va2[0], pre2[0], lg);
                float d1 = fdot2(va2[1], pre2[1], 0.f);
                float d2 = fdot2(va2[2], pre2[2], 0.f);
                float d3 = fdot2(va2[3], pre2[3], 0.f);
                d0 = fdot2(va2[4], pre2[4], d0);
                d1 = fdot2(va2[5], pre2[5], d1);
                d2 = fdot2(va2[6], pre2[6], d2);
                d3 = fdot2(va2[7], pre2[7], d3);
                lg = (d0 + d1) + (d2 + d3);
            }
        }

        // ---- store: lanes i<4 each write one float4 quad -> fully coalesced ----
        if (iI < 4) {
            // quad q=iI covers pairs j0=2(iI&1)+4((iI>>1)&1), j0+1
            h2 h0 = hsel((iI & 2) != 0, pre2[4], pre2[0]);
            h2 h1 = hsel((iI & 2) != 0, pre2[5], pre2[1]);
            h2 h2_ = hsel((iI & 2) != 0, pre2[6], pre2[2]);
            h2 h3 = hsel((iI & 2) != 0, pre2[7], pre2[3]);
            h2 p0 = hsel((iI & 1) != 0, h2_, h0);
            h2 p1 = hsel((iI & 1) != 0, h3, h1);
            float4 o4 = make_float4((float)p0.x, (float)p0.y,
                                    (float)p1.x, (float)p1.y);
            const int p = ((u0 + w) << 1) + rh;
            const int q = ((v0 + pixl) << 1) + rw;
            *(float4*)(out + (((bp * 112 + p) * 112 + q) << 7) + cI * 16 + iI * 4) = o4;
        }
    }
}

extern "C" void kernel_launch(void* const* d_in, const int* in_sizes, int n_in,
                              void* d_out, int out_size, void* d_ws, size_t ws_size,
                              hipStream_t stream) {
    const float* x  = (const float*)d_in[0];
    const float* Wt = (const float*)d_in[1];
    const float* b  = (const float*)d_in[2];
    float* out = (float*)d_out;
    _Float16* wb = (_Float16*)d_ws;          // 4 parities x 16384 f16 = 64 KB

    prep_w<<<32, 256, 0, stream>>>(Wt, wb);
    dim3 grid(196, 4, 4);    // 14x14 4x4-pixel tiles, 4 parity classes, 4 b'
    caps_mfma<<<grid, 256, 0, stream>>>(x, wb, b, out);
}

// Round 3
// 123.959 us; speedup vs baseline: 2.8272x; 1.2161x over previous
//
#include <hip/hip_runtime.h>
#include <math.h>

#define CEPS 1e-9f

typedef _Float16 half8 __attribute__((ext_vector_type(8)));
typedef _Float16 h2 __attribute__((ext_vector_type(2)));
typedef __fp16 fp16x2 __attribute__((ext_vector_type(2)));
typedef float floatx16 __attribute__((ext_vector_type(16)));
typedef float f32x4v __attribute__((ext_vector_type(4)));

// x  : [4,56,56,8,32] fp32    W: [4,4,128,32] fp32    bias: [128] fp32
// out: [4,112,112,128] fp32 act
//
// R15: occupancy 4->5 waves/SIMD, spill-free. History:
//  R12: 75us, (256,4), 60 VGPR + 64 AGPR = 124 regs -> 4 waves, occ 38%,
//       VALU 48%, MFMA 7%, HBM 8% => latency-bound.
//  R13: (256,6)=85-reg cap + full-unroll af-CSE (+32 live) -> 950B/thread
//       spill, 326us.
//  R14: asm-laundered af addresses cut spill 4.7x (203B/thread), 94us.
//       Routing live-set ~90 regs still exceeds the 85 cap.
//  R15: (256,5) -> 102-reg cap. Demand ~90-92 fits with margin. 5 waves.
// Structure (from R13/R14):
//  (a) xt/scx share one 16.9KB LDS buffer (xt dead after K-loop).
//  (b) K-loop in two 2-n-tile passes, acc=32 AGPR; votes pkrtz-packed to
//      32 h2 VGPRs (f16 round-trip exact -> va2 bits identical to R12).
//  (c) af LDS addresses laundered through empty asm per (half,s) +
//      sched_barrier between halves: prevents cross-half load CSE/pipelining
//      that would re-extend liveness (R13 lesson).
//  (d) nq / logit fdot2 chains split 4-way (dep latency 32cy -> ~10cy).

template<int CTRL>
__device__ __forceinline__ float dpp_add(float v) {
    return v + __int_as_float(__builtin_amdgcn_update_dpp(
        0, __float_as_int(v), CTRL, 0xF, 0xF, false));
}
template<int CTRL>
__device__ __forceinline__ h2 dpp_add_h2(h2 v) {
    int t = __builtin_amdgcn_update_dpp(
        0, __builtin_bit_cast(int, v), CTRL, 0xF, 0xF, false);
    return v + __builtin_bit_cast(h2, t);
}
// sum over the 8-lane i-group (lane bits 0..2), both f16 components in parallel
__device__ __forceinline__ h2 sum_i8_h2(h2 v) {
    v = dpp_add_h2<0xB1>(v);     // quad_perm xor1
    v = dpp_add_h2<0x4E>(v);     // quad_perm xor2
    v = dpp_add_h2<0x141>(v);    // row_half_mirror (cross-quad)
    return v;
}
__device__ __forceinline__ h2 pkrtz(float a, float b) {
    return __builtin_bit_cast(h2, __builtin_amdgcn_cvt_pkrtz(a, b));
}
__device__ __forceinline__ float fdot2(h2 a, h2 b, float c) {
    return __builtin_amdgcn_fdot2(__builtin_bit_cast(fp16x2, a),
                                  __builtin_bit_cast(fp16x2, b), c, false);
}
__device__ __forceinline__ h2 hsel(bool c, h2 a, h2 b) {
    int r = c ? __builtin_bit_cast(int, a) : __builtin_bit_cast(int, b);
    return __builtin_bit_cast(h2, r);
}

// B[k][n] fragment table: idx = ((parity*8 + s)*4 + t)*64 + l -> 8 f16
__global__ __launch_bounds__(256) void prep_w(const float* __restrict__ Wt,
                                              _Float16* __restrict__ wb) {
    int idx = blockIdx.x * 256 + threadIdx.x;    // [0, 8192)
    int parity = idx >> 11;
    int s = (idx >> 8) & 7;
    int t = (idx >> 6) & 3;
    int l = idx & 63;
    int rh = parity >> 1, rw = parity & 1;
    int n = t * 32 + (l & 31);
    int h = l >> 5;
    int ci0 = ((s & 1) << 4) + (h << 3);
    int kh = ((s >> 2) << 1) + 1 - rh;
    int kw = (((s >> 1) & 1) << 1) + 1 - rw;
    const float* src = Wt + (((kh * 4 + kw) * 128 + n) << 5) + ci0;
    float4 w0 = *(const float4*)src;
    float4 w1 = *(const float4*)(src + 4);
    half8 hv;
    hv[0] = (_Float16)w0.x; hv[1] = (_Float16)w0.y;
    hv[2] = (_Float16)w0.z; hv[3] = (_Float16)w0.w;
    hv[4] = (_Float16)w1.x; hv[5] = (_Float16)w1.y;
    hv[6] = (_Float16)w1.z; hv[7] = (_Float16)w1.w;
    *(half8*)(wb + ((long)idx << 3)) = hv;
}

__global__ __launch_bounds__(256, 5) void caps_mfma(
    const float* __restrict__ x,
    const _Float16* __restrict__ wb,
    const float* __restrict__ bias,
    float* __restrict__ out)
{
    // Shared buffer, two lifetimes:
    //  phase 1 (stage + K-loop): xt = [cell(5x5)][i(8)][ci padded 32->40] f16, 16000 B
    //  phase 2 (routing):        scx = [wave(4)][1056] f32 transpose scratch, 16896 B
    __shared__ __align__(16) unsigned char smem[4 * 1056 * 4];
    _Float16* xt = (_Float16*)smem;
    float (*scx)[1056] = (float (*)[1056])smem;

    const int tid = threadIdx.x;
    const int tile = blockIdx.x;            // 0..195 : 14x14 tiles of 4x4 pixels
    const int tu = tile / 14, tv = tile - tu * 14;
    const int u0 = tu * 4, v0 = tv * 4;
    const int rh = blockIdx.y >> 1;         // p & 1
    const int rw = blockIdx.y & 1;          // q & 1
    const int bp = blockIdx.z;              // b'
    const _Float16* wsrc = wb + ((long)blockIdx.y << 14);   // parity slice, 16 KB

    // ---- stage x: fp32 -> f16 tile [ri(5)][rj(5)][i(8)][ci], zero-filled OOB ----
    #pragma unroll
    for (int it = 0; it < 4; ++it) {
        int idx = tid + (it << 8);
        if (idx < 800) {
            int cell = idx >> 5;            // 0..24
            int r = idx & 31;
            int i = r >> 2;
            int ci0 = (r & 3) << 3;
            int ri = cell / 5, rj = cell - ri * 5;
            int gi = u0 + rh - 1 + ri;
            int gj = v0 + rw - 1 + rj;
            float tmp[8] = {0.f, 0.f, 0.f, 0.f, 0.f, 0.f, 0.f, 0.f};
            if ((unsigned)gi < 56u && (unsigned)gj < 56u) {
                const float* src = x + (((i & 3) * 56 + gi) * 56 + gj) * 256
                                     + ((bp * 2 + (i >> 2)) << 5) + ci0;
                float4 a0 = *(const float4*)src;
                float4 a1 = *(const float4*)(src + 4);
                tmp[0] = a0.x; tmp[1] = a0.y; tmp[2] = a0.z; tmp[3] = a0.w;
                tmp[4] = a1.x; tmp[5] = a1.y; tmp[6] = a1.z; tmp[7] = a1.w;
            }
            half8 hv;
            #pragma unroll
            for (int j = 0; j < 8; ++j) hv[j] = (_Float16)tmp[j];
            *(half8*)(xt + (cell * 8 + i) * 40 + ci0) = hv;
        }
    }
    __syncthreads();

    const int l = tid & 63;
    const int w = tid >> 6;                 // wave = u-row within tile
    const int col = l & 31, h = l >> 5;
    const int invA = (l & 31) * 40 + (h << 3);

    // ---- MFMA K-loop, TWO passes of 2 n-tiles: acc is 32 AGPR (not 64). ----
    // After each pass, pack f32 acc -> f16 pairs along j (= pixl*4+il):
    // pf[t][m] = (votes[j=2m], votes[j=2m+1]) at ca = 32t+col.
    h2 pf[4][8];
    #pragma unroll
    for (int half = 0; half < 2; ++half) {
        floatx16 acc0, acc1;
        #pragma unroll
        for (int j = 0; j < 16; ++j) { acc0[j] = 0.f; acc1[j] = 0.f; }
        const int tb = half << 1;
        #pragma unroll
        for (int s = 0; s < 8; ++s) {
            const int tkh = s >> 2;
            const int tkw = (s >> 1) & 1;
            const int row = w + 1 - tkh;
            int aoff = (row * 5 + 1 - tkw) * 320 + ((s & 1) << 4) + invA;
            // SPILL FIX (R14): make the A-frag address opaque so the
            // compiler cannot CSE/hoist the 8 identical xt loads across the
            // two halves (R13: that hoisting (+32 VGPR) caused the spill).
            asm("" : "+v"(aoff));
            half8 af = *(const half8*)(xt + aoff);
            half8 bf0 = *(const half8*)(wsrc + (((s * 4 + tb) * 64 + l) << 3));
            half8 bf1 = *(const half8*)(wsrc + (((s * 4 + tb + 1) * 64 + l) << 3));
            acc0 = __builtin_amdgcn_mfma_f32_32x32x16_f16(af, bf0, acc0, 0, 0, 0);
            acc1 = __builtin_amdgcn_mfma_f32_32x32x16_f16(af, bf1, acc1, 0, 0, 0);
        }
        #pragma unroll
        for (int m = 0; m < 8; ++m) {
            pf[tb][m]     = pkrtz(acc0[2 * m], acc0[2 * m + 1]);
            pf[tb + 1][m] = pkrtz(acc1[2 * m], acc1[2 * m + 1]);
        }
        // keep half-2's loads from being software-pipelined into half-1
        // (would extend acc/af liveness across the packing)
        __builtin_amdgcn_sched_barrier(0);
    }

    // xt is dead; scx aliases it. All waves must pass here before writing.
    __syncthreads();

    // ---- routing: lane = (c = l>>3, i = l&7); a(16) in-register as h2[8] ----
    float* scb = &scx[w][0];                // wave-local after the barrier
    const int cI = l >> 3;
    const int iI = l & 7;

    // bias as packed f16 pairs, loaded once (8 distinct addrs/wave -> L1)
    h2 bq2[8];
    {
        const float* bpt = bias + (cI << 4);
        float4 b0 = *(const float4*)bpt;
        float4 b1 = *(const float4*)(bpt + 4);
        float4 b2 = *(const float4*)(bpt + 8);
        float4 b3 = *(const float4*)(bpt + 12);
        bq2[0] = pkrtz(b0.x, b0.y); bq2[1] = pkrtz(b0.z, b0.w);
        bq2[2] = pkrtz(b1.x, b1.y); bq2[3] = pkrtz(b1.z, b1.w);
        bq2[4] = pkrtz(b2.x, b2.y); bq2[5] = pkrtz(b2.z, b2.w);
        bq2[6] = pkrtz(b3.x, b3.y); bq2[7] = pkrtz(b3.z, b3.w);
    }
    const h2 c0125 = pkrtz(0.125f, 0.125f);

    #pragma unroll
    for (int pixl = 0; pixl < 4; ++pixl) {
        // transpose: packed f16 votes -> [i][ca] f32 (row stride 132); i = 4h + il
        // (f16->f32 is exact; the later pkrtz re-pack gives bit-identical va2.)
        #pragma unroll
        for (int t = 0; t < 4; ++t)
            #pragma unroll
            for (int il = 0; il < 4; ++il) {
                h2 pp = pf[t][(pixl << 1) + (il >> 1)];
                float v = (il & 1) ? (float)pp.y : (float)pp.x;
                scb[((h << 2) + il) * 132 + t * 32 + col] = v;
            }

        // read my (c,i) row: 4x ds_read_b128, convert to 8 packed f16 pairs
        const float* rb = scb + iI * 132 + (cI << 4);
        f32x4v vq0 = *(const f32x4v*)(rb);
        f32x4v vq1 = *(const f32x4v*)(rb + 4);
        f32x4v vq2 = *(const f32x4v*)(rb + 8);
        f32x4v vq3 = *(const f32x4v*)(rb + 12);
        h2 va2[8];
        va2[0] = pkrtz(vq0.x, vq0.y); va2[1] = pkrtz(vq0.z, vq0.w);
        va2[2] = pkrtz(vq1.x, vq1.y); va2[3] = pkrtz(vq1.z, vq1.w);
        va2[4] = pkrtz(vq2.x, vq2.y); va2[5] = pkrtz(vq2.z, vq2.w);
        va2[6] = pkrtz(vq3.x, vq3.y); va2[7] = pkrtz(vq3.z, vq3.w);

        h2 pre2[8];
        float lg;

        // ---- round 0: route = 1/8 ----
        #pragma unroll
        for (int j = 0; j < 8; ++j) {
            h2 s2 = sum_i8_h2(va2[j]);
            pre2[j] = s2 * c0125 + bq2[j];           // v_pk_fma_f16
        }
        {
            float n0 = fdot2(pre2[0], pre2[0], 0.f);
            float n1 = fdot2(pre2[1], pre2[1], 0.f);
            float n2 = fdot2(pre2[2], pre2[2], 0.f);
            float n3 = fdot2(pre2[3], pre2[3], 0.f);
            n0 = fdot2(pre2[4], pre2[4], n0);
            n1 = fdot2(pre2[5], pre2[5], n1);
            n2 = fdot2(pre2[6], pre2[6], n2);
            n3 = fdot2(pre2[7], pre2[7], n3);
            float nq = (n0 + n1) + (n2 + n3);
            float sc = nq * __builtin_amdgcn_rcpf(1.f + nq)
                          * __builtin_amdgcn_rsqf(nq + CEPS);
            h2 sc2 = pkrtz(sc, sc);
            #pragma unroll
            for (int j = 0; j < 8; ++j) pre2[j] *= sc2;   // pre2 = act
            float d0 = fdot2(va2[0], pre2[0], 0.f);
            float d1 = fdot2(va2[1], pre2[1], 0.f);
            float d2 = fdot2(va2[2], pre2[2], 0.f);
            float d3 = fdot2(va2[3], pre2[3], 0.f);
            d0 = fdot2(va2[4], pre2[4], d0);
            d1 = fdot2(va2[5], pre2[5], d1);
            d2 = fdot2(va2[6], pre2[6], d2);
            d3 = fdot2(va2[7], pre2[7], d3);
            lg = (d0 + d1) + (d2 + d3);               // per-(i,c), fp32
        }

        // ---- rounds 1,2 ----
        #pragma unroll
        for (int r = 1; r < 3; ++r) {
            // softmax over c (lane bits 3..5); logits bounded, no max-sub; fp32
            float e = __expf(lg);
            float ss = dpp_add<0x128>(e);             // ror8 == xor8 (in-row)
            ss += __int_as_float(__builtin_amdgcn_ds_swizzle(
                      __float_as_int(ss), 0x401F));   // xor16
            ss += __shfl_xor(ss, 32);
            float route = e * __builtin_amdgcn_rcpf(ss);
            h2 rt2 = pkrtz(route, route);
            #pragma unroll
            for (int j = 0; j < 8; ++j) {
                h2 p = sum_i8_h2(rt2 * va2[j]);       // pk_mul + packed i-sum
                pre2[j] = p + bq2[j];                 // v_pk_add_f16
            }
            float n0 = fdot2(pre2[0], pre2[0], 0.f);
            float n1 = fdot2(pre2[1], pre2[1], 0.f);
            float n2 = fdot2(pre2[2], pre2[2], 0.f);
            float n3 = fdot2(pre2[3], pre2[3], 0.f);
            n0 = fdot2(pre2[4], pre2[4], n0);
            n1 = fdot2(pre2[5], pre2[5], n1);
            n2 = fdot2(pre2[6], pre2[6], n2);
            n3 = fdot2(pre2[7], pre2[7], n3);
            float nq = (n0 + n1) + (n2 + n3);
            float sc = nq * __builtin_amdgcn_rcpf(1.f + nq)
                          * __builtin_amdgcn_rsqf(nq + CEPS);
            h2 sc2 = pkrtz(sc, sc);
            #pragma unroll
            for (int j = 0; j < 8; ++j) pre2[j] *= sc2;   // act
            if (r < 2) {
                float d0 = fdot2(va2[0], pre2[0], lg);
                float d1 = fdot2(va2[1], pre2[1], 0.f);
                float d2 = fdot2(va2[2], pre2[2], 0.f);
                float d3 = fdot2(va2[3], pre2[3], 0.f);
                d0 = fdot2(va2[4], pre2[4], d0);
                d1 = fdot2(va2[5], pre2[5], d1);
                d2 = fdot2(va2[6], pre2[6], d2);
                d3 = fdot2(va2[7], pre2[7], d3);
                lg = (d0 + d1) + (d2 + d3);
            }
        }

        // ---- store: lanes i<4 each write one float4 quad -> fully coalesced ----
        if (iI < 4) {
            // quad q=iI covers pairs j0=2(iI&1)+4((iI>>1)&1), j0+1
            h2 h0 = hsel((iI & 2) != 0, pre2[4], pre2[0]);
            h2 h1 = hsel((iI & 2) != 0, pre2[5], pre2[1]);
            h2 h2_ = hsel((iI & 2) != 0, pre2[6], pre2[2]);
            h2 h3 = hsel((iI & 2) != 0, pre2[7], pre2[3]);
            h2 p0 = hsel((iI & 1) != 0, h2_, h0);
            h2 p1 = hsel((iI & 1) != 0, h3, h1);
            float4 o4 = make_float4((float)p0.x, (float)p0.y,
                                    (float)p1.x, (float)p1.y);
            const int p = ((u0 + w) << 1) + rh;
            const int q = ((v0 + pixl) << 1) + rw;
            *(float4*)(out + (((bp * 112 + p) * 112 + q) << 7) + cI * 16 + iI * 4) = o4;
        }
    }
}

extern "C" void kernel_launch(void* const* d_in, const int* in_sizes, int n_in,
                              void* d_out, int out_size, void* d_ws, size_t ws_size,
                              hipStream_t stream) {
    const float* x  = (const float*)d_in[0];
    const float* Wt = (const float*)d_in[1];
    const float* b  = (const float*)d_in[2];
    float* out = (float*)d_out;
    _Float16* wb = (_Float16*)d_ws;          // 4 parities x 16384 f16 = 64 KB

    prep_w<<<32, 256, 0, stream>>>(Wt, wb);
    dim3 grid(196, 4, 4);    // 14x14 4x4-pixel tiles, 4 parity classes, 4 b'
    caps_mfma<<<grid, 256, 0, stream>>>(x, wb, b, out);
}